// Round 12
// baseline (427.691 us; speedup 1.0000x reference)
//
#include <hip/hip_runtime.h>
#include <hip/hip_bf16.h>
#include <math.h>

#define SEQ 2048
#define BATCH 4
#define DM 512
#define NH 8
#define HD 64
#define HID 2048
#define ROWS (BATCH * SEQ)

typedef __attribute__((ext_vector_type(8))) short short8;
typedef __attribute__((ext_vector_type(4))) float f32x4;

__device__ __forceinline__ short f2bf(float f) {
    unsigned u = __float_as_uint(f);
    u += 0x7fff + ((u >> 16) & 1);   // RNE
    return (short)(u >> 16);
}

// async global->LDS DMA, 16 B per lane; LDS dest must be wave-uniform base + lane*16
__device__ __forceinline__ void gl2lds16(const void* g, void* l) {
    __builtin_amdgcn_global_load_lds(
        (const __attribute__((address_space(1))) void*)g,
        (__attribute__((address_space(3))) void*)l, 16, 0, 0);
}

// ---- prep_k: ALL input-only work in one launch (tcast + ln1 + bias repack) -
// The three parts have zero mutual deps (read weights / x / bias resp.).
// 7168 blocks, 3:2:2 interleave -> every CU gets a mix; the HBM-bound repack
// overlaps the transpose + LN instead of serializing behind them.
// R11 counters proved the repack (~80us @2.2TB/s, occ 9%) dominated qkvbias_k
// while its GEMM part was ~5us MFMA-busy -> give repack a bigger partner.
__global__ __launch_bounds__(256) void prep_k(
    const float* __restrict__ qkv_w, const float* __restrict__ out_w,
    const float* __restrict__ w1, const float* __restrict__ w2,
    short* __restrict__ o_qkv, short* __restrict__ o_out,
    short* __restrict__ o_w1, short* __restrict__ o_w2,
    const float* __restrict__ X, const float* __restrict__ lg,
    const float* __restrict__ lb, short* __restrict__ Y,
    const float* __restrict__ bias, short* __restrict__ biasP) {
    __shared__ __attribute__((aligned(16))) char smem[33024];
    int bid = blockIdx.x;
    int grp = bid / 7, sub = bid % 7;
    int t = threadIdx.x;

    if (sub < 3) {
        // ---------------- weight transpose+cast tile (tcast_all body) -------
        float (*tile)[33] = (float(*)[33])smem;
        int id = grp * 3 + sub;            // 0..3071
        const float* W; short* O; int K, N;
        if (id < 768)       { W = qkv_w; O = o_qkv; K = 512;  N = 1536; }
        else if (id < 1024) { W = out_w; O = o_out; K = 512;  N = 512;  id -= 768; }
        else if (id < 2048) { W = w1;    O = o_w1;  K = 512;  N = 2048; id -= 1024; }
        else                { W = w2;    O = o_w2;  K = 2048; N = 512;  id -= 2048; }
        int tn = N / 32;
        int n0 = (id % tn) * 32, k0 = (id / tn) * 32;
        int tx = t & 31, ty = t >> 5;      // flattened dim3(32,8)
#pragma unroll
        for (int i = 0; i < 4; ++i)
            tile[ty + i * 8][tx] = W[(size_t)(k0 + ty + i * 8) * N + n0 + tx];
        __syncthreads();
#pragma unroll
        for (int i = 0; i < 4; ++i)
            O[(size_t)(n0 + ty + i * 8) * K + k0 + tx] = f2bf(tile[tx][ty + i * 8]);
    } else if (sub < 5) {
        // ---------------- layernorm (ln_k body), 4 rows/block ---------------
        int lbk = grp * 2 + (sub - 3);     // 0..2047
        int wv = t >> 6, ln = t & 63;
        size_t row = (size_t)lbk * 4 + wv;
        const float* xr = X + row * DM;
        float4 v0 = *(const float4*)(xr + ln * 4);
        float4 v1 = *(const float4*)(xr + 256 + ln * 4);
        float s = v0.x + v0.y + v0.z + v0.w + v1.x + v1.y + v1.z + v1.w;
        float q = v0.x * v0.x + v0.y * v0.y + v0.z * v0.z + v0.w * v0.w +
                  v1.x * v1.x + v1.y * v1.y + v1.z * v1.z + v1.w * v1.w;
#pragma unroll
        for (int off = 1; off < 64; off <<= 1) {
            s += __shfl_xor(s, off);
            q += __shfl_xor(q, off);
        }
        float mean = s * (1.0f / 512.0f);
        float var = q * (1.0f / 512.0f) - mean * mean;
        float rstd = rsqrtf(var + 1e-5f);
        int c0 = ln * 4, c1 = 256 + ln * 4;
        ushort4 o0, o1;
        o0.x = (unsigned short)f2bf((v0.x - mean) * rstd * lg[c0 + 0] + lb[c0 + 0]);
        o0.y = (unsigned short)f2bf((v0.y - mean) * rstd * lg[c0 + 1] + lb[c0 + 1]);
        o0.z = (unsigned short)f2bf((v0.z - mean) * rstd * lg[c0 + 2] + lb[c0 + 2]);
        o0.w = (unsigned short)f2bf((v0.w - mean) * rstd * lg[c0 + 3] + lb[c0 + 3]);
        o1.x = (unsigned short)f2bf((v1.x - mean) * rstd * lg[c1 + 0] + lb[c1 + 0]);
        o1.y = (unsigned short)f2bf((v1.y - mean) * rstd * lg[c1 + 1] + lb[c1 + 1]);
        o1.z = (unsigned short)f2bf((v1.z - mean) * rstd * lg[c1 + 2] + lb[c1 + 2]);
        o1.w = (unsigned short)f2bf((v1.w - mean) * rstd * lg[c1 + 3] + lb[c1 + 3]);
        *(ushort4*)((unsigned short*)Y + row * DM + c0) = o0;
        *(ushort4*)((unsigned short*)Y + row * DM + c1) = o1;
    } else {
        // ---------------- bias repack tile (bias_prep v3 body) --------------
        typedef short (*tile1032)[1032];
        tile1032 tl = (tile1032)smem;
        int id = grp * 2 + (sub - 5);      // 0..2047 = (h*128+g)*2 + half
        int w = t >> 6, ln = t & 63, quad = ln >> 4, l15 = ln & 15;
        int half = id & 1;
        int g = (id >> 1) & 127;
        int h = id >> 8;
        const float* src = bias + (size_t)h * SEQ * SEQ + (size_t)g * 16 * SEQ + half * 1024;
#pragma unroll
        for (int i = 0; i < 16; ++i) {
            float4 v = *(const float4*)(src + (size_t)i * SEQ + t * 4);
            float2 lo, hi;
            lo.x = v.x * 1.44269504f; lo.y = v.y * 1.44269504f;
            hi.x = v.z * 1.44269504f; hi.y = v.w * 1.44269504f;
            __hip_bfloat162 l2 = __float22bfloat162_rn(lo);
            __hip_bfloat162 h2 = __float22bfloat162_rn(hi);
            uint2 pp;
            pp.x = *(unsigned*)&l2;
            pp.y = *(unsigned*)&h2;
            *(uint2*)&tl[i][t * 4] = pp;
        }
        __syncthreads();
        int jtbase = half * 16;
#pragma unroll
        for (int u = 0; u < 4; ++u) {
            int jl = w * 4 + u;
            int tau = (h * 128 + g) * 32 + jtbase + jl;
#pragma unroll
            for (int n2 = 0; n2 < 2; ++n2) {
                uint2 a = *(const uint2*)&tl[l15][jl * 64 + n2 * 32 + quad * 4];
                uint2 b = *(const uint2*)&tl[l15][jl * 64 + n2 * 32 + 16 + quad * 4];
                uint4 pp;
                pp.x = a.x; pp.y = a.y; pp.z = b.x; pp.w = b.y;
                *(uint4*)(biasP + (size_t)tau * 1024 + n2 * 512 + ln * 8) = pp;
            }
        }
    }
}

// ---------------- layernorm standalone (for ln2) ----------------------------
__global__ __launch_bounds__(256) void ln_k(const float* __restrict__ X,
                                            const float* __restrict__ g,
                                            const float* __restrict__ bta,
                                            short* __restrict__ Y) {
    int t = threadIdx.x;
    int wv = t >> 6, ln = t & 63;
    size_t row = (size_t)blockIdx.x * 4 + wv;
    const float* xr = X + row * DM;
    float4 v0 = *(const float4*)(xr + ln * 4);
    float4 v1 = *(const float4*)(xr + 256 + ln * 4);
    float s = v0.x + v0.y + v0.z + v0.w + v1.x + v1.y + v1.z + v1.w;
    float q = v0.x * v0.x + v0.y * v0.y + v0.z * v0.z + v0.w * v0.w +
              v1.x * v1.x + v1.y * v1.y + v1.z * v1.z + v1.w * v1.w;
#pragma unroll
    for (int off = 1; off < 64; off <<= 1) {
        s += __shfl_xor(s, off);
        q += __shfl_xor(q, off);
    }
    float mean = s * (1.0f / 512.0f);
    float var = q * (1.0f / 512.0f) - mean * mean;
    float rstd = rsqrtf(var + 1e-5f);
    int c0 = ln * 4, c1 = 256 + ln * 4;
    ushort4 o0, o1;
    o0.x = (unsigned short)f2bf((v0.x - mean) * rstd * g[c0 + 0] + bta[c0 + 0]);
    o0.y = (unsigned short)f2bf((v0.y - mean) * rstd * g[c0 + 1] + bta[c0 + 1]);
    o0.z = (unsigned short)f2bf((v0.z - mean) * rstd * g[c0 + 2] + bta[c0 + 2]);
    o0.w = (unsigned short)f2bf((v0.w - mean) * rstd * g[c0 + 3] + bta[c0 + 3]);
    o1.x = (unsigned short)f2bf((v1.x - mean) * rstd * g[c1 + 0] + bta[c1 + 0]);
    o1.y = (unsigned short)f2bf((v1.y - mean) * rstd * g[c1 + 1] + bta[c1 + 1]);
    o1.z = (unsigned short)f2bf((v1.z - mean) * rstd * g[c1 + 2] + bta[c1 + 2]);
    o1.w = (unsigned short)f2bf((v1.w - mean) * rstd * g[c1 + 3] + bta[c1 + 3]);
    *(ushort4*)((unsigned short*)Y + row * DM + c0) = o0;
    *(ushort4*)((unsigned short*)Y + row * DM + c1) = o1;
}

// ---------------- GEMM v4: 2-phase dbuf, template BM, EPI3 added ------------
// EPI 0: bf16 C+bias ; 1: bf16 gelu(C+bias) ; 2: fp32 res+(C+bias)*gamma ;
// 3: qkv special (ldc=1024, q-cols scaled 0.125*log2e, v-cols -> vT in Cout2).
template <int EPI, int TN, int BM>
__global__ __launch_bounds__(256) void gemm_bt(const short* __restrict__ A,
                                               const short* __restrict__ Bt,
                                               const float* __restrict__ bias,
                                               const float* __restrict__ gamma,
                                               const float* __restrict__ res,
                                               void* __restrict__ Cout,
                                               short* __restrict__ Cout2,
                                               int M, int N, int K, int gx) {
    constexpr int NI = TN / 32;   // B-fragment sets per wave
    constexpr int MI = BM / 32;   // A-fragment sets per wave
    __shared__ __attribute__((aligned(16))) short As[2][2][BM][32];
    __shared__ __attribute__((aligned(16))) short Bs[2][2][TN][32];
    int t = threadIdx.x;
    int w = t >> 6, ln = t & 63;
    int quad = ln >> 4, l15 = ln & 15;
    int nwg = gridDim.x;
    int qq = nwg >> 3;
    int sw = ((blockIdx.x & 7) * qq) + (blockIdx.x >> 3);
    int bx = sw % gx, by = sw / gx;
    int n0 = bx * TN, m0 = by * BM;
    int wm = (w & 1) * (BM / 2), wn = (w >> 1) * (TN / 2);

    int srow0 = w * 32 + (ln >> 2);     // 128-row staging (2 loads/lane/half)
    int srow1 = srow0 + 16;
    int srowH = w * 16 + (ln >> 2);     // 64-row staging (1 load/lane/half)
    int schunk = (ln & 3) * 8;
    const short* Ag0 = A + (size_t)(m0 + srow0) * K + schunk;
    const short* Ag1 = A + (size_t)(m0 + srow1) * K + schunk;
    const short* AgH = A + (size_t)(m0 + srowH) * K + schunk;
    const short* Bg0 = Bt + (size_t)(n0 + srow0) * K + schunk;
    const short* Bg1 = Bt + (size_t)(n0 + srow1) * K + schunk;
    const short* BgH = Bt + (size_t)(n0 + srowH) * K + schunk;

    f32x4 acc[MI][NI];
#pragma unroll
    for (int i = 0; i < MI; ++i)
#pragma unroll
        for (int j = 0; j < NI; ++j) acc[i][j] = (f32x4){0.f, 0.f, 0.f, 0.f};

    auto STAGE = [&](int buf, int k0) {
        if constexpr (BM == 128) {
            gl2lds16(Ag0 + k0, &As[buf][0][srow0][schunk]);
            gl2lds16(Ag1 + k0, &As[buf][0][srow1][schunk]);
            gl2lds16(Ag0 + k0 + 32, &As[buf][1][srow0][schunk]);
            gl2lds16(Ag1 + k0 + 32, &As[buf][1][srow1][schunk]);
        } else {
            gl2lds16(AgH + k0, &As[buf][0][srowH][schunk]);
            gl2lds16(AgH + k0 + 32, &As[buf][1][srowH][schunk]);
        }
        if constexpr (TN == 128) {
            gl2lds16(Bg0 + k0, &Bs[buf][0][srow0 & 127][schunk]);
            gl2lds16(Bg1 + k0, &Bs[buf][0][srow1 & 127][schunk]);
            gl2lds16(Bg0 + k0 + 32, &Bs[buf][1][srow0 & 127][schunk]);
            gl2lds16(Bg1 + k0 + 32, &Bs[buf][1][srow1 & 127][schunk]);
        } else {
            gl2lds16(BgH + k0, &Bs[buf][0][srowH & (TN - 1)][schunk]);
            gl2lds16(BgH + k0 + 32, &Bs[buf][1][srowH & (TN - 1)][schunk]);
        }
    };

    // prologue: stage step 0; barrier drains it (compiler vmcnt(0))
    STAGE(0, 0);
    __syncthreads();

    int NS = K >> 6;
    for (int s = 0; s < NS; ++s) {
        int cur = s & 1;
        if (s + 1 < NS) STAGE(cur ^ 1, (s + 1) << 6);   // async, overlaps compute
#pragma unroll
        for (int hh = 0; hh < 2; ++hh) {
            short8 af[MI], bf[NI];
#pragma unroll
            for (int mi = 0; mi < MI; ++mi)
                af[mi] = *(const short8*)&As[cur][hh][wm + mi * 16 + l15][quad * 8];
#pragma unroll
            for (int ni = 0; ni < NI; ++ni)
                bf[ni] = *(const short8*)&Bs[cur][hh][wn + ni * 16 + l15][quad * 8];
#pragma unroll
            for (int mi = 0; mi < MI; ++mi)
#pragma unroll
                for (int ni = 0; ni < NI; ++ni)
                    acc[mi][ni] = __builtin_amdgcn_mfma_f32_16x16x32_bf16(
                        af[mi], bf[ni], acc[mi][ni], 0, 0, 0);
        }
        __syncthreads();
    }

    if (EPI == 3 && n0 >= 1024) {
        // v-part: transposed store vT[(b*8+h)][d][key], 4 consecutive keys/lane
#pragma unroll
        for (int mi = 0; mi < MI; ++mi) {
#pragma unroll
            for (int ni = 0; ni < NI; ++ni) {
                int col = n0 + wn + ni * 16 + l15;
                int d = col - 1024, hh2 = d >> 6, dd = d & 63;
                int row0 = m0 + wm + mi * 16 + quad * 4;
                int bb = row0 >> 11, key = row0 & 2047;
                float bs = bias[col];
                ushort4 pk;
                pk.x = (unsigned short)f2bf(acc[mi][ni][0] + bs);
                pk.y = (unsigned short)f2bf(acc[mi][ni][1] + bs);
                pk.z = (unsigned short)f2bf(acc[mi][ni][2] + bs);
                pk.w = (unsigned short)f2bf(acc[mi][ni][3] + bs);
                *(ushort4*)&Cout2[((size_t)(bb * 8 + hh2) * 64 + dd) * 2048 + key] = pk;
            }
        }
    } else {
#pragma unroll
        for (int mi = 0; mi < MI; ++mi) {
#pragma unroll
            for (int ni = 0; ni < NI; ++ni) {
#pragma unroll
                for (int r = 0; r < 4; ++r) {
                    int row = m0 + wm + mi * 16 + quad * 4 + r;
                    int col = n0 + wn + ni * 16 + l15;
                    float v = acc[mi][ni][r] + bias[col];
                    if (EPI == 0) {
                        ((short*)Cout)[(size_t)row * N + col] = f2bf(v);
                    } else if (EPI == 1) {
                        // gelu_tanh = v * sigmoid(2*0.79788456*(v+0.044715 v^3))
                        float u = v * fmaf(v * v, 0.0713548162f, 1.59576912f);
                        float gg = v / (1.0f + __expf(-u));
                        ((short*)Cout)[(size_t)row * N + col] = f2bf(gg);
                    } else if (EPI == 2) {
                        ((float*)Cout)[(size_t)row * N + col] =
                            fmaf(v, gamma[col], res[(size_t)row * N + col]);
                    } else {  // EPI 3, q/k cols, ldc = 1024
                        float sc = (n0 < 512) ? 0.18033688f : 1.0f;  // 0.125*log2e
                        ((short*)Cout)[(size_t)row * 1024 + col] = f2bf(v * sc);
                    }
                }
            }
        }
    }
}

// ---------------- flash attention v10: uint4 frag-bias loads (R9 best) ------
__global__ __launch_bounds__(256, 3) void attn_k(const short* __restrict__ qkv,
                                                 const short* __restrict__ vT,
                                                 const short* __restrict__ biasP,
                                                 short* __restrict__ Aout) {
    __shared__ __attribute__((aligned(16))) short Ks[2][64 * 64];
    __shared__ __attribute__((aligned(16))) short Vs[2][64 * 64];
    __shared__ __attribute__((aligned(16))) short Ps[4][2][16 * 64];
    int t = threadIdx.x;
    int w = t >> 6, ln = t & 63, quad = ln >> 4, l15 = ln & 15;
    int idx = blockIdx.x;
    int h = idx & 7, b = (idx >> 3) & 3, qt = idx >> 5;  // qt 0..15
    int qb = qt * 128 + w * 16;          // qg0: qb.., qg1: qb+64..
    const size_t cbase = (size_t)b * SEQ * 1024;

    // Q fragments (B-operand), pre-scaled by 0.125*log2e in qkv epilogue
    const short* qrow0 = qkv + cbase + (size_t)(qb + l15) * 1024 + h * 64;
    const short* qrow1 = qrow0 + (size_t)64 * 1024;
    short8 qf[2][2];
    qf[0][0] = *(const short8*)(qrow0 + quad * 8);
    qf[0][1] = *(const short8*)(qrow0 + 32 + quad * 8);
    qf[1][0] = *(const short8*)(qrow1 + quad * 8);
    qf[1][1] = *(const short8*)(qrow1 + 32 + quad * 8);

    // DMA staging: lane covers LDS chunk t*16B = (kr,kc); source pre-swizzled
    int kr = t >> 3, kc = t & 7;                    // kr 0..31, kc 0..7
    int sc = (kc ^ (kr & 7)) * 8;                   // swizzled 16B chunk (shorts)
    const short* kgS = qkv + cbase + 512 + h * 64 + sc;             // + (j+row)*1024
    const short* vgS = vT + (size_t)(b * 8 + h) * 64 * 2048 + sc;   // + d*2048 + j

    // biasP v3 pointers: g = qt*8 + w + qg*4 ; addr = base + jt*1024 + n2*512 + ln*8
    int g0 = qt * 8 + w;
    const short* bp0 = biasP + ((size_t)(h * 128 + g0) * 32) * 1024 + ln * 8;
    const short* bp1 = biasP + ((size_t)(h * 128 + g0 + 4) * 32) * 1024 + ln * 8;

    short8 ones;
#pragma unroll
    for (int i = 0; i < 8; ++i) ones[i] = (short)0x3F80;  // bf16 1.0

    f32x4 o[2][4], ol[2];
#pragma unroll
    for (int qg = 0; qg < 2; ++qg) {
#pragma unroll
        for (int db = 0; db < 4; ++db) o[qg][db] = (f32x4){0.f, 0.f, 0.f, 0.f};
        ol[qg] = (f32x4){0.f, 0.f, 0.f, 0.f};
    }

    int sw7 = l15 & 7;

    // ---- prologue: DMA tile 0 into buffer 0; prefetch bias regs ----
    gl2lds16(kgS,                              &Ks[0][t * 8]);
    gl2lds16(kgS + (size_t)32 * 1024,          &Ks[0][2048 + t * 8]);
    gl2lds16(vgS,                              &Vs[0][t * 8]);
    gl2lds16(vgS + (size_t)32 * 2048,          &Vs[0][2048 + t * 8]);
    uint4 bbc[2][2];
#pragma unroll
    for (int n2 = 0; n2 < 2; ++n2) {
        bbc[0][n2] = *(const uint4*)(bp0 + n2 * 512);
        bbc[1][n2] = *(const uint4*)(bp1 + n2 * 512);
    }

    int cur = 0;
    for (int jt = 0; jt < 32; ++jt) {
        __syncthreads();   // drains DMA -> buf[cur] ready; buf[nxt] free
        int jn = (jt < 31) ? (jt + 1) : jt;
        int j1 = jn * 64;
        int nxt = cur ^ 1;
        gl2lds16(kgS + (size_t)(j1 + kr) * 1024,      &Ks[nxt][t * 8]);
        gl2lds16(kgS + (size_t)(j1 + 32 + kr) * 1024, &Ks[nxt][2048 + t * 8]);
        gl2lds16(vgS + (size_t)kr * 2048 + j1,        &Vs[nxt][t * 8]);
        gl2lds16(vgS + (size_t)(32 + kr) * 2048 + j1, &Vs[nxt][2048 + t * 8]);

        // S^T = K Q^T + biasP (as accumulator init)
        // lane holds (key = ni*16 + quad*4 + r, q = l15) per qg
        f32x4 s4[2][4];
#pragma unroll
        for (int ni = 0; ni < 4; ++ni) {
            short8 k0 = *(const short8*)&Ks[cur][(ni * 16 + l15) * 64 + ((quad ^ sw7) * 8)];
            short8 k1 = *(const short8*)&Ks[cur][(ni * 16 + l15) * 64 + (((4 + quad) ^ sw7) * 8)];
#pragma unroll
            for (int qg = 0; qg < 2; ++qg) {
                uint4 bb = bbc[qg][ni >> 1];
                unsigned lo = (ni & 1) ? bb.z : bb.x;
                unsigned hi = (ni & 1) ? bb.w : bb.y;
                f32x4 z;
                z[0] = __uint_as_float(lo << 16);
                z[1] = __uint_as_float(lo & 0xffff0000u);
                z[2] = __uint_as_float(hi << 16);
                z[3] = __uint_as_float(hi & 0xffff0000u);
                z = __builtin_amdgcn_mfma_f32_16x16x32_bf16(k0, qf[qg][0], z, 0, 0, 0);
                s4[qg][ni] = __builtin_amdgcn_mfma_f32_16x16x32_bf16(k1, qf[qg][1], z, 0, 0, 0);
            }
        }
        // reload bias for jt+1 (consumed next iteration; exp2+PV covers latency)
#pragma unroll
        for (int n2 = 0; n2 < 2; ++n2) {
            bbc[0][n2] = *(const uint4*)(bp0 + (size_t)jn * 1024 + n2 * 512);
            bbc[1][n2] = *(const uint4*)(bp1 + (size_t)jn * 1024 + n2 * 512);
        }
        // softmax: p = exp2(s); pack bf16; swizzled P write.
#pragma unroll
        for (int qg = 0; qg < 2; ++qg) {
#pragma unroll
            for (int ni = 0; ni < 4; ++ni) {
                float2 plo, phi;
                plo.x = exp2f(s4[qg][ni][0]);
                plo.y = exp2f(s4[qg][ni][1]);
                phi.x = exp2f(s4[qg][ni][2]);
                phi.y = exp2f(s4[qg][ni][3]);
                __hip_bfloat162 l2 = __float22bfloat162_rn(plo);
                __hip_bfloat162 h2 = __float22bfloat162_rn(phi);
                union { uint2 u; } pp;
                pp.u.x = *(unsigned*)&l2;
                pp.u.y = *(unsigned*)&h2;
                int c = ni * 2 + (quad >> 1);
                *(uint2*)&Ps[w][qg][l15 * 64 + ((c ^ sw7) * 8) + (quad & 1) * 4] = pp.u;
            }
        }
        // O += P V ; l += P 1  (wave-private Ps: lgkmcnt ordering, no barrier)
#pragma unroll
        for (int kk = 0; kk < 2; ++kk) {
            short8 ap0 = *(const short8*)&Ps[w][0][l15 * 64 + (((kk * 4 + quad) ^ sw7) * 8)];
            short8 ap1 = *(const short8*)&Ps[w][1][l15 * 64 + (((kk * 4 + quad) ^ sw7) * 8)];
#pragma unroll
            for (int db = 0; db < 4; ++db) {
                short8 vv = *(const short8*)&Vs[cur][(db * 16 + l15) * 64 + (((kk * 4 + quad) ^ sw7) * 8)];
                o[0][db] = __builtin_amdgcn_mfma_f32_16x16x32_bf16(ap0, vv, o[0][db], 0, 0, 0);
                o[1][db] = __builtin_amdgcn_mfma_f32_16x16x32_bf16(ap1, vv, o[1][db], 0, 0, 0);
            }
            ol[0] = __builtin_amdgcn_mfma_f32_16x16x32_bf16(ap0, ones, ol[0], 0, 0, 0);
            ol[1] = __builtin_amdgcn_mfma_f32_16x16x32_bf16(ap1, ones, ol[1], 0, 0, 0);
        }
        cur = nxt;
    }
    // epilogue: normalize, bf16 out; row q = qb + qg*64 + quad*4 + r
#pragma unroll
    for (int qg = 0; qg < 2; ++qg) {
#pragma unroll
        for (int r = 0; r < 4; ++r) {
            float inv = 1.0f / ol[qg][r];
            int qrow_g = b * SEQ + qb + qg * 64 + quad * 4 + r;
#pragma unroll
            for (int db = 0; db < 4; ++db) {
                Aout[(size_t)qrow_g * DM + h * 64 + db * 16 + l15] =
                    f2bf(o[qg][db][r] * inv);
            }
        }
    }
}

extern "C" void kernel_launch(void* const* d_in, const int* in_sizes, int n_in,
                              void* d_out, int out_size, void* d_ws, size_t ws_size,
                              hipStream_t stream) {
    const float* x      = (const float*)d_in[0];
    const float* bias   = (const float*)d_in[1];
    const float* qkv_w  = (const float*)d_in[2];
    const float* qkv_b  = (const float*)d_in[3];
    const float* out_w  = (const float*)d_in[4];
    const float* out_b  = (const float*)d_in[5];
    const float* ln1_w  = (const float*)d_in[6];
    const float* ln1_b  = (const float*)d_in[7];
    const float* ln2_w  = (const float*)d_in[8];
    const float* ln2_b  = (const float*)d_in[9];
    const float* ffn_w1 = (const float*)d_in[10];
    const float* ffn_b1 = (const float*)d_in[11];
    const float* ffn_w2 = (const float*)d_in[12];
    const float* ffn_b2 = (const float*)d_in[13];
    const float* gamma1 = (const float*)d_in[14];
    const float* gamma2 = (const float*)d_in[15];
    float* out = (float*)d_out;

    short* wqkvT = (short*)d_ws;                         // [1536][512]
    short* woutT = wqkvT + (size_t)1536 * 512;           // [512][512]
    short* w1T   = woutT + (size_t)512 * 512;            // [2048][512]
    short* w2T   = w1T + (size_t)2048 * 512;             // [512][2048]
    short* y1    = w2T + (size_t)512 * 2048;             // [8192][512]
    short* qkvB  = y1 + (size_t)ROWS * DM;               // [8192][1024] (q,k)
    short* vTb   = qkvB + (size_t)ROWS * 1024;           // [32][64][2048] (v^T)
    short* aoutB = vTb + (size_t)32 * 64 * 2048;         // [8192][512]
    float* x1    = (float*)(aoutB + (size_t)ROWS * DM);  // [8192][512] fp32
    short* biasPw = (short*)(x1 + (size_t)ROWS * DM);    // [8][2048][2048] bf16 frag
    short* hB    = qkvB;  // ffn hidden [8192][2048] reuses qkvB+vT

    // all input-only work fused (tcast + ln1 + bias repack), 3:2:2 interleave
    prep_k<<<7168, 256, 0, stream>>>(qkv_w, out_w, ffn_w1, ffn_w2,
                                     wqkvT, woutT, w1T, w2T,
                                     x, ln1_w, ln1_b, y1,
                                     bias, biasPw);
    gemm_bt<3, 128, 128><<<768, 256, 0, stream>>>(
        y1, wqkvT, qkv_b, nullptr, nullptr, qkvB, vTb, ROWS, 1536, 512, 12);
    attn_k<<<512, 256, 0, stream>>>(qkvB, vTb, biasPw, aoutB);
    gemm_bt<2, 128, 64><<<512, 256, 0, stream>>>(
        aoutB, woutT, out_b, gamma1, x, x1, nullptr, ROWS, 512, 512, 4);
    ln_k<<<ROWS / 4, 256, 0, stream>>>(x1, ln2_w, ln2_b, y1);
    gemm_bt<1, 128, 128><<<1024, 256, 0, stream>>>(
        y1, w1T, ffn_b1, nullptr, nullptr, hB, nullptr, ROWS, 2048, 512, 16);
    gemm_bt<2, 128, 64><<<512, 256, 0, stream>>>(
        hB, w2T, ffn_b2, gamma2, x1, out, nullptr, ROWS, 512, 2048, 4);
}

// Round 13
// 418.423 us; speedup vs baseline: 1.0221x; 1.0221x over previous
//
#include <hip/hip_runtime.h>
#include <hip/hip_bf16.h>
#include <math.h>

#define SEQ 2048
#define BATCH 4
#define DM 512
#define NH 8
#define HD 64
#define HID 2048
#define ROWS (BATCH * SEQ)

typedef __attribute__((ext_vector_type(8))) short short8;
typedef __attribute__((ext_vector_type(4))) float f32x4;

__device__ __forceinline__ short f2bf(float f) {
    unsigned u = __float_as_uint(f);
    u += 0x7fff + ((u >> 16) & 1);   // RNE
    return (short)(u >> 16);
}

// async global->LDS DMA, 16 B per lane; LDS dest must be wave-uniform base + lane*16
__device__ __forceinline__ void gl2lds16(const void* g, void* l) {
    __builtin_amdgcn_global_load_lds(
        (const __attribute__((address_space(1))) void*)g,
        (__attribute__((address_space(3))) void*)l, 16, 0, 0);
}

// ------------- fused weight transpose+cast: 4 matrices, one launch ----------
__global__ __launch_bounds__(256) void tcast_all(
    const float* __restrict__ qkv_w, const float* __restrict__ out_w,
    const float* __restrict__ w1, const float* __restrict__ w2,
    short* __restrict__ o_qkv, short* __restrict__ o_out,
    short* __restrict__ o_w1, short* __restrict__ o_w2) {
    __shared__ float tile[32][33];
    int id = blockIdx.x;
    const float* W; short* O; int K, N;
    if (id < 768)       { W = qkv_w; O = o_qkv; K = 512;  N = 1536; }
    else if (id < 1024) { W = out_w; O = o_out; K = 512;  N = 512;  id -= 768; }
    else if (id < 2048) { W = w1;    O = o_w1;  K = 512;  N = 2048; id -= 1024; }
    else                { W = w2;    O = o_w2;  K = 2048; N = 512;  id -= 2048; }
    int tn = N / 32;
    int n0 = (id % tn) * 32, k0 = (id / tn) * 32;
    int tx = threadIdx.x, ty = threadIdx.y;
#pragma unroll
    for (int i = 0; i < 4; ++i)
        tile[ty + i * 8][tx] = W[(size_t)(k0 + ty + i * 8) * N + n0 + tx];
    __syncthreads();
#pragma unroll
    for (int i = 0; i < 4; ++i)
        O[(size_t)(n0 + ty + i * 8) * K + k0 + tx] = f2bf(tile[tx][ty + i * 8]);
}

// ---------------- layernorm: fp32 [rows][512] -> bf16, one wave per row -----
__global__ __launch_bounds__(256) void ln_k(const float* __restrict__ X,
                                            const float* __restrict__ g,
                                            const float* __restrict__ bta,
                                            short* __restrict__ Y) {
    int t = threadIdx.x;
    int wv = t >> 6, ln = t & 63;
    size_t row = (size_t)blockIdx.x * 4 + wv;
    const float* xr = X + row * DM;
    float4 v0 = *(const float4*)(xr + ln * 4);
    float4 v1 = *(const float4*)(xr + 256 + ln * 4);
    float s = v0.x + v0.y + v0.z + v0.w + v1.x + v1.y + v1.z + v1.w;
    float q = v0.x * v0.x + v0.y * v0.y + v0.z * v0.z + v0.w * v0.w +
              v1.x * v1.x + v1.y * v1.y + v1.z * v1.z + v1.w * v1.w;
#pragma unroll
    for (int off = 1; off < 64; off <<= 1) {
        s += __shfl_xor(s, off);
        q += __shfl_xor(q, off);
    }
    float mean = s * (1.0f / 512.0f);
    float var = q * (1.0f / 512.0f) - mean * mean;
    float rstd = rsqrtf(var + 1e-5f);
    int c0 = ln * 4, c1 = 256 + ln * 4;
    ushort4 o0, o1;
    o0.x = (unsigned short)f2bf((v0.x - mean) * rstd * g[c0 + 0] + bta[c0 + 0]);
    o0.y = (unsigned short)f2bf((v0.y - mean) * rstd * g[c0 + 1] + bta[c0 + 1]);
    o0.z = (unsigned short)f2bf((v0.z - mean) * rstd * g[c0 + 2] + bta[c0 + 2]);
    o0.w = (unsigned short)f2bf((v0.w - mean) * rstd * g[c0 + 3] + bta[c0 + 3]);
    o1.x = (unsigned short)f2bf((v1.x - mean) * rstd * g[c1 + 0] + bta[c1 + 0]);
    o1.y = (unsigned short)f2bf((v1.y - mean) * rstd * g[c1 + 1] + bta[c1 + 1]);
    o1.z = (unsigned short)f2bf((v1.z - mean) * rstd * g[c1 + 2] + bta[c1 + 2]);
    o1.w = (unsigned short)f2bf((v1.w - mean) * rstd * g[c1 + 3] + bta[c1 + 3]);
    *(ushort4*)((unsigned short*)Y + row * DM + c0) = o0;
    *(ushort4*)((unsigned short*)Y + row * DM + c1) = o1;
}

// ---------------- GEMM v3: 2-phase dbuf + template BM (R11 verbatim) --------
template <int EPI, int TN, int BM>
__global__ __launch_bounds__(256) void gemm_bt(const short* __restrict__ A,
                                               const short* __restrict__ Bt,
                                               const float* __restrict__ bias,
                                               const float* __restrict__ gamma,
                                               const float* __restrict__ res,
                                               void* __restrict__ Cout,
                                               int M, int N, int K, int gx) {
    constexpr int NI = TN / 32;   // B-fragment sets per wave
    constexpr int MI = BM / 32;   // A-fragment sets per wave
    __shared__ __attribute__((aligned(16))) short As[2][2][BM][32];
    __shared__ __attribute__((aligned(16))) short Bs[2][2][TN][32];
    int t = threadIdx.x;
    int w = t >> 6, ln = t & 63;
    int quad = ln >> 4, l15 = ln & 15;
    int nwg = gridDim.x;
    int qq = nwg >> 3;
    int sw = ((blockIdx.x & 7) * qq) + (blockIdx.x >> 3);
    int bx = sw % gx, by = sw / gx;
    int n0 = bx * TN, m0 = by * BM;
    int wm = (w & 1) * (BM / 2), wn = (w >> 1) * (TN / 2);

    int srow0 = w * 32 + (ln >> 2);     // 128-row staging (2 loads/lane/half)
    int srow1 = srow0 + 16;
    int srowH = w * 16 + (ln >> 2);     // 64-row staging (1 load/lane/half)
    int schunk = (ln & 3) * 8;
    const short* Ag0 = A + (size_t)(m0 + srow0) * K + schunk;
    const short* Ag1 = A + (size_t)(m0 + srow1) * K + schunk;
    const short* AgH = A + (size_t)(m0 + srowH) * K + schunk;
    const short* Bg0 = Bt + (size_t)(n0 + srow0) * K + schunk;
    const short* Bg1 = Bt + (size_t)(n0 + srow1) * K + schunk;
    const short* BgH = Bt + (size_t)(n0 + srowH) * K + schunk;

    f32x4 acc[MI][NI];
#pragma unroll
    for (int i = 0; i < MI; ++i)
#pragma unroll
        for (int j = 0; j < NI; ++j) acc[i][j] = (f32x4){0.f, 0.f, 0.f, 0.f};

    auto STAGE = [&](int buf, int k0) {
        if constexpr (BM == 128) {
            gl2lds16(Ag0 + k0, &As[buf][0][srow0][schunk]);
            gl2lds16(Ag1 + k0, &As[buf][0][srow1][schunk]);
            gl2lds16(Ag0 + k0 + 32, &As[buf][1][srow0][schunk]);
            gl2lds16(Ag1 + k0 + 32, &As[buf][1][srow1][schunk]);
        } else {
            gl2lds16(AgH + k0, &As[buf][0][srowH][schunk]);
            gl2lds16(AgH + k0 + 32, &As[buf][1][srowH][schunk]);
        }
        if constexpr (TN == 128) {
            gl2lds16(Bg0 + k0, &Bs[buf][0][srow0 & 127][schunk]);
            gl2lds16(Bg1 + k0, &Bs[buf][0][srow1 & 127][schunk]);
            gl2lds16(Bg0 + k0 + 32, &Bs[buf][1][srow0 & 127][schunk]);
            gl2lds16(Bg1 + k0 + 32, &Bs[buf][1][srow1 & 127][schunk]);
        } else {
            gl2lds16(BgH + k0, &Bs[buf][0][srowH & (TN - 1)][schunk]);
            gl2lds16(BgH + k0 + 32, &Bs[buf][1][srowH & (TN - 1)][schunk]);
        }
    };

    // prologue: stage step 0; barrier drains it (compiler vmcnt(0))
    STAGE(0, 0);
    __syncthreads();

    int NS = K >> 6;
    for (int s = 0; s < NS; ++s) {
        int cur = s & 1;
        if (s + 1 < NS) STAGE(cur ^ 1, (s + 1) << 6);   // async, overlaps compute
#pragma unroll
        for (int hh = 0; hh < 2; ++hh) {
            short8 af[MI], bf[NI];
#pragma unroll
            for (int mi = 0; mi < MI; ++mi)
                af[mi] = *(const short8*)&As[cur][hh][wm + mi * 16 + l15][quad * 8];
#pragma unroll
            for (int ni = 0; ni < NI; ++ni)
                bf[ni] = *(const short8*)&Bs[cur][hh][wn + ni * 16 + l15][quad * 8];
#pragma unroll
            for (int mi = 0; mi < MI; ++mi)
#pragma unroll
                for (int ni = 0; ni < NI; ++ni)
                    acc[mi][ni] = __builtin_amdgcn_mfma_f32_16x16x32_bf16(
                        af[mi], bf[ni], acc[mi][ni], 0, 0, 0);
        }
        __syncthreads();
    }

#pragma unroll
    for (int mi = 0; mi < MI; ++mi) {
#pragma unroll
        for (int ni = 0; ni < NI; ++ni) {
#pragma unroll
            for (int r = 0; r < 4; ++r) {
                int row = m0 + wm + mi * 16 + quad * 4 + r;
                int col = n0 + wn + ni * 16 + l15;
                float v = acc[mi][ni][r] + bias[col];
                if (EPI == 0) {
                    ((short*)Cout)[(size_t)row * N + col] = f2bf(v);
                } else if (EPI == 1) {
                    // gelu_tanh = v * sigmoid(2*0.79788456*(v+0.044715 v^3))
                    float u = v * fmaf(v * v, 0.0713548162f, 1.59576912f);
                    float gg = v / (1.0f + __expf(-u));
                    ((short*)Cout)[(size_t)row * N + col] = f2bf(gg);
                } else {  // EPI 2
                    ((float*)Cout)[(size_t)row * N + col] =
                        fmaf(v, gamma[col], res[(size_t)row * N + col]);
                }
            }
        }
    }
}

// -------- fused qkv GEMM + bias repack: heterogeneous blocks (R11 verbatim) -
__global__ __launch_bounds__(256) void qkvbias_k(
    const short* __restrict__ A, const short* __restrict__ Bt,
    const float* __restrict__ qkvb, short* __restrict__ Cout,
    short* __restrict__ Cout2,
    const float* __restrict__ bias, short* __restrict__ biasP) {
    __shared__ __attribute__((aligned(16))) char smem[33024];
    int bid = blockIdx.x;
    int grp = bid / 11, sub = bid % 11;
    int t = threadIdx.x;
    int w = t >> 6, ln = t & 63;
    int quad = ln >> 4, l15 = ln & 15;

    if (sub < 3) {
        // ---------------- qkv GEMM tile (EPI3, TN=128) ----------------
        typedef short (*tile32)[32];
        tile32 As0 = (tile32)smem;
        tile32 As1 = (tile32)(smem + 8192);
        tile32 Bs0 = (tile32)(smem + 16384);
        tile32 Bs1 = (tile32)(smem + 24576);
        const int K = 512, N = 1536;
        int g = grp * 3 + sub;               // 0..767
        int n0 = (g % 12) * 128, m0 = (g / 12) * 128;
        int wm = (w & 1) * 64, wn = (w >> 1) * 64;

        int srow0 = w * 32 + (ln >> 2);
        int srow1 = srow0 + 16;
        int schunk = (ln & 3) * 8;
        const short* Ag0 = A + (size_t)(m0 + srow0) * K + schunk;
        const short* Ag1 = A + (size_t)(m0 + srow1) * K + schunk;
        const short* Bg0 = Bt + (size_t)(n0 + srow0) * K + schunk;
        const short* Bg1 = Bt + (size_t)(n0 + srow1) * K + schunk;

        f32x4 acc[4][4];
#pragma unroll
        for (int i = 0; i < 4; ++i)
#pragma unroll
            for (int j = 0; j < 4; ++j) acc[i][j] = (f32x4){0.f, 0.f, 0.f, 0.f};

        for (int k0 = 0; k0 < K; k0 += 64) {
            __syncthreads();
            gl2lds16(Ag0 + k0, &As0[srow0][schunk]);
            gl2lds16(Ag1 + k0, &As0[srow1][schunk]);
            gl2lds16(Ag0 + k0 + 32, &As1[srow0][schunk]);
            gl2lds16(Ag1 + k0 + 32, &As1[srow1][schunk]);
            gl2lds16(Bg0 + k0, &Bs0[srow0][schunk]);
            gl2lds16(Bg1 + k0, &Bs0[srow1][schunk]);
            gl2lds16(Bg0 + k0 + 32, &Bs1[srow0][schunk]);
            gl2lds16(Bg1 + k0 + 32, &Bs1[srow1][schunk]);
            __syncthreads();
            {
                short8 af[4], bf[4];
#pragma unroll
                for (int mi = 0; mi < 4; ++mi)
                    af[mi] = *(const short8*)&As0[wm + mi * 16 + l15][quad * 8];
#pragma unroll
                for (int ni = 0; ni < 4; ++ni)
                    bf[ni] = *(const short8*)&Bs0[wn + ni * 16 + l15][quad * 8];
#pragma unroll
                for (int mi = 0; mi < 4; ++mi)
#pragma unroll
                    for (int ni = 0; ni < 4; ++ni)
                        acc[mi][ni] = __builtin_amdgcn_mfma_f32_16x16x32_bf16(
                            af[mi], bf[ni], acc[mi][ni], 0, 0, 0);
            }
            {
                short8 af[4], bf[4];
#pragma unroll
                for (int mi = 0; mi < 4; ++mi)
                    af[mi] = *(const short8*)&As1[wm + mi * 16 + l15][quad * 8];
#pragma unroll
                for (int ni = 0; ni < 4; ++ni)
                    bf[ni] = *(const short8*)&Bs1[wn + ni * 16 + l15][quad * 8];
#pragma unroll
                for (int mi = 0; mi < 4; ++mi)
#pragma unroll
                    for (int ni = 0; ni < 4; ++ni)
                        acc[mi][ni] = __builtin_amdgcn_mfma_f32_16x16x32_bf16(
                            af[mi], bf[ni], acc[mi][ni], 0, 0, 0);
            }
        }

        if (n0 >= 1024) {
            // v-part: transposed store vT[(b*8+h)][d][key]
#pragma unroll
            for (int mi = 0; mi < 4; ++mi) {
#pragma unroll
                for (int ni = 0; ni < 4; ++ni) {
                    int col = n0 + wn + ni * 16 + l15;
                    int d = col - 1024, hh = d >> 6, dd = d & 63;
                    int row0 = m0 + wm + mi * 16 + quad * 4;
                    int bb = row0 >> 11, key = row0 & 2047;
                    float bs = qkvb[col];
                    ushort4 pk;
                    pk.x = (unsigned short)f2bf(acc[mi][ni][0] + bs);
                    pk.y = (unsigned short)f2bf(acc[mi][ni][1] + bs);
                    pk.z = (unsigned short)f2bf(acc[mi][ni][2] + bs);
                    pk.w = (unsigned short)f2bf(acc[mi][ni][3] + bs);
                    *(ushort4*)&Cout2[((size_t)(bb * 8 + hh) * 64 + dd) * 2048 + key] = pk;
                }
            }
        } else {
#pragma unroll
            for (int mi = 0; mi < 4; ++mi) {
#pragma unroll
                for (int ni = 0; ni < 4; ++ni) {
#pragma unroll
                    for (int r = 0; r < 4; ++r) {
                        int row = m0 + wm + mi * 16 + quad * 4 + r;
                        int col = n0 + wn + ni * 16 + l15;
                        float v = acc[mi][ni][r] + qkvb[col];
                        float sc = (n0 < 512) ? 0.18033688f : 1.0f;  // 0.125*log2e
                        Cout[(size_t)row * 1024 + col] = f2bf(v * sc);
                    }
                }
            }
        }
    } else {
        // ---------------- bias repack tile (bias_prep v3) ----------------
        typedef short (*tile1032)[1032];
        tile1032 tl = (tile1032)smem;
        int id = grp * 8 + (sub - 3);        // 0..2047 = (h*128+g)*2 + half
        int half = id & 1;
        int g = (id >> 1) & 127;
        int h = id >> 8;
        const float* src = bias + (size_t)h * SEQ * SEQ + (size_t)g * 16 * SEQ + half * 1024;
#pragma unroll
        for (int i = 0; i < 16; ++i) {
            float4 v = *(const float4*)(src + (size_t)i * SEQ + t * 4);
            float2 lo, hi;
            lo.x = v.x * 1.44269504f; lo.y = v.y * 1.44269504f;
            hi.x = v.z * 1.44269504f; hi.y = v.w * 1.44269504f;
            __hip_bfloat162 l2 = __float22bfloat162_rn(lo);
            __hip_bfloat162 h2 = __float22bfloat162_rn(hi);
            uint2 pp;
            pp.x = *(unsigned*)&l2;
            pp.y = *(unsigned*)&h2;
            *(uint2*)&tl[i][t * 4] = pp;
        }
        __syncthreads();
        int jtbase = half * 16;
#pragma unroll
        for (int u = 0; u < 4; ++u) {
            int jl = w * 4 + u;
            int tau = (h * 128 + g) * 32 + jtbase + jl;
#pragma unroll
            for (int n2 = 0; n2 < 2; ++n2) {
                uint2 a = *(const uint2*)&tl[l15][jl * 64 + n2 * 32 + quad * 4];
                uint2 b = *(const uint2*)&tl[l15][jl * 64 + n2 * 32 + 16 + quad * 4];
                uint4 pp;
                pp.x = a.x; pp.y = a.y; pp.z = b.x; pp.w = b.y;
                *(uint4*)(biasP + (size_t)tau * 1024 + n2 * 512 + ln * 8) = pp;
            }
        }
    }
}

// ---------------- flash attention v12: v10 + s_setprio on MFMA clusters -----
// T5 (catalog): +4-7% measured on attn (m191) when waves have role diversity.
// Our 4 waves sync once per jt and diverge within it (wave-private Ps) ->
// setprio(1) keeps the MFMA-issuing wave fed while peers issue loads/exp2.
__global__ __launch_bounds__(256, 3) void attn_k(const short* __restrict__ qkv,
                                                 const short* __restrict__ vT,
                                                 const short* __restrict__ biasP,
                                                 short* __restrict__ Aout) {
    __shared__ __attribute__((aligned(16))) short Ks[2][64 * 64];
    __shared__ __attribute__((aligned(16))) short Vs[2][64 * 64];
    __shared__ __attribute__((aligned(16))) short Ps[4][2][16 * 64];
    int t = threadIdx.x;
    int w = t >> 6, ln = t & 63, quad = ln >> 4, l15 = ln & 15;
    int idx = blockIdx.x;
    int h = idx & 7, b = (idx >> 3) & 3, qt = idx >> 5;  // qt 0..15
    int qb = qt * 128 + w * 16;          // qg0: qb.., qg1: qb+64..
    const size_t cbase = (size_t)b * SEQ * 1024;

    // Q fragments (B-operand), pre-scaled by 0.125*log2e in qkv epilogue
    const short* qrow0 = qkv + cbase + (size_t)(qb + l15) * 1024 + h * 64;
    const short* qrow1 = qrow0 + (size_t)64 * 1024;
    short8 qf[2][2];
    qf[0][0] = *(const short8*)(qrow0 + quad * 8);
    qf[0][1] = *(const short8*)(qrow0 + 32 + quad * 8);
    qf[1][0] = *(const short8*)(qrow1 + quad * 8);
    qf[1][1] = *(const short8*)(qrow1 + 32 + quad * 8);

    // DMA staging: lane covers LDS chunk t*16B = (kr,kc); source pre-swizzled
    int kr = t >> 3, kc = t & 7;                    // kr 0..31, kc 0..7
    int sc = (kc ^ (kr & 7)) * 8;                   // swizzled 16B chunk (shorts)
    const short* kgS = qkv + cbase + 512 + h * 64 + sc;             // + (j+row)*1024
    const short* vgS = vT + (size_t)(b * 8 + h) * 64 * 2048 + sc;   // + d*2048 + j

    // biasP v3 pointers: g = qt*8 + w + qg*4 ; addr = base + jt*1024 + n2*512 + ln*8
    int g0 = qt * 8 + w;
    const short* bp0 = biasP + ((size_t)(h * 128 + g0) * 32) * 1024 + ln * 8;
    const short* bp1 = biasP + ((size_t)(h * 128 + g0 + 4) * 32) * 1024 + ln * 8;

    short8 ones;
#pragma unroll
    for (int i = 0; i < 8; ++i) ones[i] = (short)0x3F80;  // bf16 1.0

    f32x4 o[2][4], ol[2];
#pragma unroll
    for (int qg = 0; qg < 2; ++qg) {
#pragma unroll
        for (int db = 0; db < 4; ++db) o[qg][db] = (f32x4){0.f, 0.f, 0.f, 0.f};
        ol[qg] = (f32x4){0.f, 0.f, 0.f, 0.f};
    }

    int sw7 = l15 & 7;

    // ---- prologue: DMA tile 0 into buffer 0; prefetch bias regs ----
    gl2lds16(kgS,                              &Ks[0][t * 8]);
    gl2lds16(kgS + (size_t)32 * 1024,          &Ks[0][2048 + t * 8]);
    gl2lds16(vgS,                              &Vs[0][t * 8]);
    gl2lds16(vgS + (size_t)32 * 2048,          &Vs[0][2048 + t * 8]);
    uint4 bbc[2][2];
#pragma unroll
    for (int n2 = 0; n2 < 2; ++n2) {
        bbc[0][n2] = *(const uint4*)(bp0 + n2 * 512);
        bbc[1][n2] = *(const uint4*)(bp1 + n2 * 512);
    }

    int cur = 0;
    for (int jt = 0; jt < 32; ++jt) {
        __syncthreads();   // drains DMA -> buf[cur] ready; buf[nxt] free
        int jn = (jt < 31) ? (jt + 1) : jt;
        int j1 = jn * 64;
        int nxt = cur ^ 1;
        gl2lds16(kgS + (size_t)(j1 + kr) * 1024,      &Ks[nxt][t * 8]);
        gl2lds16(kgS + (size_t)(j1 + 32 + kr) * 1024, &Ks[nxt][2048 + t * 8]);
        gl2lds16(vgS + (size_t)kr * 2048 + j1,        &Vs[nxt][t * 8]);
        gl2lds16(vgS + (size_t)(32 + kr) * 2048 + j1, &Vs[nxt][2048 + t * 8]);

        // S^T = K Q^T + biasP (as accumulator init)
        // lane holds (key = ni*16 + quad*4 + r, q = l15) per qg
        f32x4 s4[2][4];
        __builtin_amdgcn_s_setprio(1);
#pragma unroll
        for (int ni = 0; ni < 4; ++ni) {
            short8 k0 = *(const short8*)&Ks[cur][(ni * 16 + l15) * 64 + ((quad ^ sw7) * 8)];
            short8 k1 = *(const short8*)&Ks[cur][(ni * 16 + l15) * 64 + (((4 + quad) ^ sw7) * 8)];
#pragma unroll
            for (int qg = 0; qg < 2; ++qg) {
                uint4 bb = bbc[qg][ni >> 1];
                unsigned lo = (ni & 1) ? bb.z : bb.x;
                unsigned hi = (ni & 1) ? bb.w : bb.y;
                f32x4 z;
                z[0] = __uint_as_float(lo << 16);
                z[1] = __uint_as_float(lo & 0xffff0000u);
                z[2] = __uint_as_float(hi << 16);
                z[3] = __uint_as_float(hi & 0xffff0000u);
                z = __builtin_amdgcn_mfma_f32_16x16x32_bf16(k0, qf[qg][0], z, 0, 0, 0);
                s4[qg][ni] = __builtin_amdgcn_mfma_f32_16x16x32_bf16(k1, qf[qg][1], z, 0, 0, 0);
            }
        }
        __builtin_amdgcn_s_setprio(0);
        // reload bias for jt+1 (consumed next iteration; exp2+PV covers latency)
#pragma unroll
        for (int n2 = 0; n2 < 2; ++n2) {
            bbc[0][n2] = *(const uint4*)(bp0 + (size_t)jn * 1024 + n2 * 512);
            bbc[1][n2] = *(const uint4*)(bp1 + (size_t)jn * 1024 + n2 * 512);
        }
        // softmax: p = exp2(s); pack bf16; swizzled P write.
#pragma unroll
        for (int qg = 0; qg < 2; ++qg) {
#pragma unroll
            for (int ni = 0; ni < 4; ++ni) {
                float2 plo, phi;
                plo.x = exp2f(s4[qg][ni][0]);
                plo.y = exp2f(s4[qg][ni][1]);
                phi.x = exp2f(s4[qg][ni][2]);
                phi.y = exp2f(s4[qg][ni][3]);
                __hip_bfloat162 l2 = __float22bfloat162_rn(plo);
                __hip_bfloat162 h2 = __float22bfloat162_rn(phi);
                union { uint2 u; } pp;
                pp.u.x = *(unsigned*)&l2;
                pp.u.y = *(unsigned*)&h2;
                int c = ni * 2 + (quad >> 1);
                *(uint2*)&Ps[w][qg][l15 * 64 + ((c ^ sw7) * 8) + (quad & 1) * 4] = pp.u;
            }
        }
        // O += P V ; l += P 1  (wave-private Ps: lgkmcnt ordering, no barrier)
        __builtin_amdgcn_s_setprio(1);
#pragma unroll
        for (int kk = 0; kk < 2; ++kk) {
            short8 ap0 = *(const short8*)&Ps[w][0][l15 * 64 + (((kk * 4 + quad) ^ sw7) * 8)];
            short8 ap1 = *(const short8*)&Ps[w][1][l15 * 64 + (((kk * 4 + quad) ^ sw7) * 8)];
#pragma unroll
            for (int db = 0; db < 4; ++db) {
                short8 vv = *(const short8*)&Vs[cur][(db * 16 + l15) * 64 + (((kk * 4 + quad) ^ sw7) * 8)];
                o[0][db] = __builtin_amdgcn_mfma_f32_16x16x32_bf16(ap0, vv, o[0][db], 0, 0, 0);
                o[1][db] = __builtin_amdgcn_mfma_f32_16x16x32_bf16(ap1, vv, o[1][db], 0, 0, 0);
            }
            ol[0] = __builtin_amdgcn_mfma_f32_16x16x32_bf16(ap0, ones, ol[0], 0, 0, 0);
            ol[1] = __builtin_amdgcn_mfma_f32_16x16x32_bf16(ap1, ones, ol[1], 0, 0, 0);
        }
        __builtin_amdgcn_s_setprio(0);
        cur = nxt;
    }
    // epilogue: normalize, bf16 out; row q = qb + qg*64 + quad*4 + r
#pragma unroll
    for (int qg = 0; qg < 2; ++qg) {
#pragma unroll
        for (int r = 0; r < 4; ++r) {
            float inv = 1.0f / ol[qg][r];
            int qrow_g = b * SEQ + qb + qg * 64 + quad * 4 + r;
#pragma unroll
            for (int db = 0; db < 4; ++db) {
                Aout[(size_t)qrow_g * DM + h * 64 + db * 16 + l15] =
                    f2bf(o[qg][db][r] * inv);
            }
        }
    }
}

extern "C" void kernel_launch(void* const* d_in, const int* in_sizes, int n_in,
                              void* d_out, int out_size, void* d_ws, size_t ws_size,
                              hipStream_t stream) {
    const float* x      = (const float*)d_in[0];
    const float* bias   = (const float*)d_in[1];
    const float* qkv_w  = (const float*)d_in[2];
    const float* qkv_b  = (const float*)d_in[3];
    const float* out_w  = (const float*)d_in[4];
    const float* out_b  = (const float*)d_in[5];
    const float* ln1_w  = (const float*)d_in[6];
    const float* ln1_b  = (const float*)d_in[7];
    const float* ln2_w  = (const float*)d_in[8];
    const float* ln2_b  = (const float*)d_in[9];
    const float* ffn_w1 = (const float*)d_in[10];
    const float* ffn_b1 = (const float*)d_in[11];
    const float* ffn_w2 = (const float*)d_in[12];
    const float* ffn_b2 = (const float*)d_in[13];
    const float* gamma1 = (const float*)d_in[14];
    const float* gamma2 = (const float*)d_in[15];
    float* out = (float*)d_out;

    short* wqkvT = (short*)d_ws;                         // [1536][512]
    short* woutT = wqkvT + (size_t)1536 * 512;           // [512][512]
    short* w1T   = woutT + (size_t)512 * 512;            // [2048][512]
    short* w2T   = w1T + (size_t)2048 * 512;             // [512][2048]
    short* y1    = w2T + (size_t)512 * 2048;             // [8192][512]
    short* qkvB  = y1 + (size_t)ROWS * DM;               // [8192][1024] (q,k)
    short* vTb   = qkvB + (size_t)ROWS * 1024;           // [32][64][2048] (v^T)
    short* aoutB = vTb + (size_t)32 * 64 * 2048;         // [8192][512]
    float* x1    = (float*)(aoutB + (size_t)ROWS * DM);  // [8192][512] fp32
    short* biasPw = (short*)(x1 + (size_t)ROWS * DM);    // [8][2048][2048] bf16 frag
    short* hB    = qkvB;  // ffn hidden [8192][2048] reuses qkvB+vT

    tcast_all<<<3072, dim3(32, 8), 0, stream>>>(qkv_w, out_w, ffn_w1, ffn_w2,
                                                wqkvT, woutT, w1T, w2T);
    ln_k<<<ROWS / 4, 256, 0, stream>>>(x, ln1_w, ln1_b, y1);
    qkvbias_k<<<2816, 256, 0, stream>>>(y1, wqkvT, qkv_b, qkvB, vTb,
                                        bias, biasPw);
    attn_k<<<512, 256, 0, stream>>>(qkvB, vTb, biasPw, aoutB);
    gemm_bt<2, 128, 64><<<512, 256, 0, stream>>>(
        aoutB, woutT, out_b, gamma1, x, x1, ROWS, 512, 512, 4);
    ln_k<<<ROWS / 4, 256, 0, stream>>>(x1, ln2_w, ln2_b, y1);
    gemm_bt<1, 128, 128><<<1024, 256, 0, stream>>>(
        y1, w1T, ffn_b1, nullptr, nullptr, hB, ROWS, 2048, 512, 16);
    gemm_bt<2, 128, 64><<<512, 256, 0, stream>>>(
        hB, w2T, ffn_b2, gamma2, x1, out, ROWS, 512, 2048, 4);
}